// Round 11
// baseline (553.490 us; speedup 1.0000x reference)
//
#include <hip/hip_runtime.h>

#define SEQ 4096
#define HID 512
#define NB  4
#define N3  1536
#define LOG2E 1.4426950408889634f

typedef _Float16 half_t;
typedef __attribute__((ext_vector_type(8))) _Float16 half8;
typedef __attribute__((ext_vector_type(4))) float f32x4;

#define GLOAD_LDS16(gp, lp) __builtin_amdgcn_global_load_lds((gp), (lp), 16, 0, 0)

#define LGKM_BARRIER()                                                       \
  asm volatile("s_waitcnt lgkmcnt(0)" ::: "memory");                         \
  __builtin_amdgcn_sched_barrier(0);                                         \
  __builtin_amdgcn_s_barrier();

// ---------------- convert x (f32) -> f16 ----------------
__global__ void k_cvt(const float* __restrict__ x, half_t* __restrict__ xh, int n4) {
  int i = blockIdx.x * blockDim.x + threadIdx.x;
  int stride = gridDim.x * blockDim.x;
  for (; i < n4; i += stride) {
    float4 v = reinterpret_cast<const float4*>(x)[i];
    union { half_t h[4]; short4 s; } u;
    u.h[0] = (half_t)v.x; u.h[1] = (half_t)v.y;
    u.h[2] = (half_t)v.z; u.h[3] = (half_t)v.w;
    reinterpret_cast<short4*>(xh)[i] = u.s;
  }
}

// ---------------- W [512][1536] f32 -> Wt [1536][512] f16 ----------------
__global__ void k_tw(const float* __restrict__ W, half_t* __restrict__ Wt) {
  __shared__ half_t tile[64][65];
  const int n0 = blockIdx.x * 64;
  const int k0 = blockIdx.y * 64;
  const int tx = threadIdx.x & 63, ty = threadIdx.x >> 6;
#pragma unroll
  for (int i = 0; i < 64; i += 4)
    tile[ty + i][tx] = (half_t)W[(size_t)(k0 + ty + i) * N3 + n0 + tx];
  __syncthreads();
#pragma unroll
  for (int i = 0; i < 64; i += 4)
    Wt[(size_t)(n0 + ty + i) * HID + k0 + tx] = tile[tx][ty + i];
}

// ---------------- QKV projection GEMM ----------------
__launch_bounds__(256)
__global__ void k_qkv(const half_t* __restrict__ xh, const half_t* __restrict__ Wt,
                      const float* __restrict__ bias,
                      half_t* __restrict__ Qh, half_t* __restrict__ Kh,
                      half_t* __restrict__ Vt) {
  __shared__ half_t sA[128 * 32];
  __shared__ half_t sB[128 * 32];
  const int t = threadIdx.x;
  const int m0 = blockIdx.y * 128;
  const int n0 = blockIdx.x * 128;
  const int lane = t & 63, wid = t >> 6;
  const int wr = (wid >> 1) * 64, wc = (wid & 1) * 64;
  const int lrow = lane & 15, lks = lane >> 4;
  const int s1 = t, s2 = t + 256;
  const int ar1 = s1 >> 2, ac1 = (s1 & 3) * 8;
  const int ar2 = s2 >> 2, ac2 = (s2 & 3) * 8;

  f32x4 acc[4][4] = {};

  for (int k0 = 0; k0 < HID; k0 += 32) {
    __syncthreads();
    GLOAD_LDS16(xh + (size_t)(m0 + ar1) * HID + k0 + ac1, &sA[s1 * 8]);
    GLOAD_LDS16(xh + (size_t)(m0 + ar2) * HID + k0 + ac2, &sA[s2 * 8]);
    GLOAD_LDS16(Wt + (size_t)(n0 + ar1) * HID + k0 + ac1, &sB[s1 * 8]);
    GLOAD_LDS16(Wt + (size_t)(n0 + ar2) * HID + k0 + ac2, &sB[s2 * 8]);
    __syncthreads();
    half8 a[4], b[4];
#pragma unroll
    for (int m = 0; m < 4; ++m)
      a[m] = *reinterpret_cast<const half8*>(&sA[(wr + m * 16 + lrow) * 32 + lks * 8]);
#pragma unroll
    for (int n = 0; n < 4; ++n)
      b[n] = *reinterpret_cast<const half8*>(&sB[(wc + n * 16 + lrow) * 32 + lks * 8]);
#pragma unroll
    for (int m = 0; m < 4; ++m)
#pragma unroll
      for (int n = 0; n < 4; ++n)
        acc[m][n] = __builtin_amdgcn_mfma_f32_16x16x32_f16(a[m], b[n], acc[m][n], 0, 0, 0);
  }

  const float scale = 0.04419417382415922f;  // 1/sqrt(512)
  const int region = n0 >> 9;  // 0=Q, 1=K, 2=V (uniform per block)
#pragma unroll
  for (int m = 0; m < 4; ++m) {
#pragma unroll
    for (int n = 0; n < 4; ++n) {
      const int col = n0 + wc + n * 16 + lrow;
#pragma unroll
      for (int r = 0; r < 4; ++r) {
        const int row = m0 + wr + m * 16 + lks * 4 + r;
        float v = acc[m][n][r] + bias[col];
        if (region == 0) {
          Qh[(size_t)row * HID + col] = (half_t)(v * scale);
        } else if (region == 1) {
          Kh[(size_t)row * HID + (col - 512)] = (half_t)v;
        } else {
          const int bb = row >> 12, ml = row & (SEQ - 1);
          Vt[((size_t)bb * HID + (col - 1024)) * SEQ + ml] = (half_t)v;
        }
      }
    }
  }
}

// ---------------- repack Vt [b][h][s] -> Vf MFMA-fragment tiles ----------------
__global__ void k_vrep(const half_t* __restrict__ Vt, half_t* __restrict__ Vf) {
  const int g = blockIdx.x * 256 + threadIdx.x;   // one half8 per thread
  const int tile = g >> 6, l = g & 63;
  const int bb = tile >> 12;
  const int kc = (tile >> 5) & 127;
  const int hg = tile & 31;
  const int h = hg * 16 + (l & 15);
  const int s = kc * 32 + (l >> 4) * 8;
  half8 v = *reinterpret_cast<const half8*>(&Vt[((size_t)bb * HID + h) * SEQ + s]);
  *reinterpret_cast<half8*>(&Vf[(size_t)tile * 512 + l * 8]) = v;
}

// ---------------- repack Kh [b*4096+key][hid] -> Kf fragment tiles ----------------
// tile (b, kg=0..255, hidc=0..15): lane l: key=kg*16+(l&15), hid=hidc*32+(l>>4)*8
__global__ void k_krep(const half_t* __restrict__ Kh, half_t* __restrict__ Kf) {
  const int g = blockIdx.x * 256 + threadIdx.x;   // one half8 per thread
  const int tile = g >> 6, l = g & 63;
  const int hidc = tile & 15;
  const int kg = (tile >> 4) & 255;
  const int bb = tile >> 12;
  const int row = bb * SEQ + kg * 16 + (l & 15);
  const int hid = hidc * 32 + (l >> 4) * 8;
  half8 v = *reinterpret_cast<const half8*>(&Kh[(size_t)row * HID + hid]);
  *reinterpret_cast<half8*>(&Kf[(size_t)tile * 512 + l * 8]) = v;
}

// ---------------- pass1: QK^T -> per-tile softmax partials ONLY (no score write) --
__launch_bounds__(256)
__global__ void k_stat(const half_t* __restrict__ Qh, const half_t* __restrict__ Kh,
                       float2* __restrict__ part) {
  __shared__ half_t sA[128 * 32];
  __shared__ half_t sB[128 * 32];
  __shared__ float lm[2][128], ls[2][128];
  const int t = threadIdx.x;
  const int bz = blockIdx.z;
  const half_t* A = Qh + (size_t)bz * SEQ * HID;
  const half_t* B = Kh + (size_t)bz * SEQ * HID;
  const int m0 = blockIdx.y * 128;
  const int n0 = blockIdx.x * 128;
  const int lane = t & 63, wid = t >> 6;
  const int wr = (wid >> 1) * 64, wc = (wid & 1) * 64;
  const int lrow = lane & 15, lks = lane >> 4;
  const int s1 = t, s2 = t + 256;
  const int ar1 = s1 >> 2, ac1 = (s1 & 3) * 8;
  const int ar2 = s2 >> 2, ac2 = (s2 & 3) * 8;

  f32x4 acc[4][4] = {};

  for (int k0 = 0; k0 < HID; k0 += 32) {
    __syncthreads();
    GLOAD_LDS16(A + (size_t)(m0 + ar1) * HID + k0 + ac1, &sA[s1 * 8]);
    GLOAD_LDS16(A + (size_t)(m0 + ar2) * HID + k0 + ac2, &sA[s2 * 8]);
    GLOAD_LDS16(B + (size_t)(n0 + ar1) * HID + k0 + ac1, &sB[s1 * 8]);
    GLOAD_LDS16(B + (size_t)(n0 + ar2) * HID + k0 + ac2, &sB[s2 * 8]);
    __syncthreads();
    half8 a[4], b[4];
#pragma unroll
    for (int m = 0; m < 4; ++m)
      a[m] = *reinterpret_cast<const half8*>(&sA[(wr + m * 16 + lrow) * 32 + lks * 8]);
#pragma unroll
    for (int n = 0; n < 4; ++n)
      b[n] = *reinterpret_cast<const half8*>(&sB[(wc + n * 16 + lrow) * 32 + lks * 8]);
#pragma unroll
    for (int m = 0; m < 4; ++m)
#pragma unroll
      for (int n = 0; n < 4; ++n)
        acc[m][n] = __builtin_amdgcn_mfma_f32_16x16x32_f16(a[m], b[n], acc[m][n], 0, 0, 0);
  }

  // per-tile softmax partials
#pragma unroll
  for (int m = 0; m < 4; ++m) {
#pragma unroll
    for (int r = 0; r < 4; ++r) {
      float mx = fmaxf(fmaxf(acc[m][0][r], acc[m][1][r]),
                       fmaxf(acc[m][2][r], acc[m][3][r]));
      mx = fmaxf(mx, __shfl_xor(mx, 1));
      mx = fmaxf(mx, __shfl_xor(mx, 2));
      mx = fmaxf(mx, __shfl_xor(mx, 4));
      mx = fmaxf(mx, __shfl_xor(mx, 8));
      float s = expf(acc[m][0][r] - mx) + expf(acc[m][1][r] - mx) +
                expf(acc[m][2][r] - mx) + expf(acc[m][3][r] - mx);
      s += __shfl_xor(s, 1);
      s += __shfl_xor(s, 2);
      s += __shfl_xor(s, 4);
      s += __shfl_xor(s, 8);
      if (lrow == 0) {
        const int rr = wr + m * 16 + lks * 4 + r;
        lm[wid & 1][rr] = mx;
        ls[wid & 1][rr] = s;
      }
    }
  }
  __syncthreads();
  if (t < 128) {
    const float m0v = lm[0][t], m1v = lm[1][t];
    const float M = fmaxf(m0v, m1v);
    const float L = ls[0][t] * expf(m0v - M) + ls[1][t] * expf(m1v - M);
    part[(size_t)(bz * SEQ + m0 + t) * 32 + blockIdx.x] = make_float2(M, L);
  }
}

// ---------------- merge 32 per-tile partials per row -> (rowmax, 1/rowsum) --------
__global__ void k_lred(const float2* __restrict__ part, float2* __restrict__ stats) {
  const int row = blockIdx.x * 256 + threadIdx.x;  // [0, NB*SEQ)
  const float2* p = part + (size_t)row * 32;
  float M = -3.4028235e38f;
#pragma unroll
  for (int i = 0; i < 32; ++i) M = fmaxf(M, p[i].x);
  float L = 0.f;
#pragma unroll
  for (int i = 0; i < 32; ++i) L += p[i].y * expf(p[i].x - M);
  stats[row] = make_float2(M, 1.0f / L);
}

// ---------------- pass2: recompute S chunk-wise, write attn, fused PV ----------
// BM=32 rows/block, 8 waves, chunk=128 keys (32 chunks). Q strip LDS-resident
// (swizzled), K/V from L2-resident fragment-packed Kf/Vf. Per chunk per wave:
// 32 QK MFMA -> exp -> f32 attn store (write-once, never read) + f16 sP (swizzled,
// double-buffered) -> 1 lgkm barrier -> 32 PV MFMA. No HBM read in the loop's
// dependence chain at all.
__launch_bounds__(512, 4)
__global__ void k_fa(const half_t* __restrict__ Qh, const half_t* __restrict__ Kf,
                     const half_t* __restrict__ Vf, const float2* __restrict__ stats,
                     float* __restrict__ attn, float* __restrict__ O) {
  __shared__ half_t sQ[32 * 512];    // 32 KB, XOR-swizzled via pre-swizzled source
  __shared__ half_t sP[4][32 * 64];  // 2 chunk-buffers x 2 halves, 16 KB
  const int t = threadIdx.x;

  // bijective XCD swizzle: 512 blocks, 64 per XCD
  const int bid = blockIdx.x;
  const int sw = (bid & 7) * 64 + (bid >> 3);
  const int bz = sw >> 7;
  const int m0 = (sw & 127) * 32;

  const int lane = t & 63, wid = t >> 6;
  const int lrow = lane & 15, lks = lane >> 4;

  float* attnb = attn + (size_t)bz * SEQ * SEQ;
  float* Ob = O + (size_t)bz * SEQ * HID;

  // ---- stage Q strip: dest linear, source column-granule XOR'd by row&7 ----
#pragma unroll
  for (int j = 0; j < 4; ++j) {
    const int row = wid + j * 8;  // 0..31
    GLOAD_LDS16(Qh + (size_t)(bz * SEQ + m0 + row) * HID + (lane ^ (row & 7)) * 8,
                &sQ[(size_t)(t + j * 512) * 8]);
  }

  // ---- per-lane softmax stats for its 8 (m,r) query rows ----
  float m2[2][4], il[2][4];
#pragma unroll
  for (int m = 0; m < 2; ++m)
#pragma unroll
    for (int r = 0; r < 4; ++r) {
      float2 st = stats[(size_t)bz * SEQ + m0 + m * 16 + lks * 4 + r];
      m2[m][r] = st.x * LOG2E;
      il[m][r] = st.y;
    }

  const int qx = lrow & 7;
  const int qb0 = lrow * 512;         // Q a-frag row base, m=0
  const int qb1 = (16 + lrow) * 512;  // m=1

  // sP PV-read offsets (swizzled, proven 0-conflict pattern)
  int aoff[2][2];
#pragma unroll
  for (int m = 0; m < 2; ++m)
#pragma unroll
    for (int kk = 0; kk < 2; ++kk) {
      const int row = m * 16 + lrow;
      aoff[m][kk] = row * 64 + (((kk * 4 + lks) ^ (row & 7)) << 3);
    }

  const half_t* const Vfb =
      Vf + (size_t)bz * 128 * 32 * 512 + (size_t)(wid * 4) * 512 + lane * 8;

  const int colw = (wid & 3) * 16 + lrow;  // sP col within 64-half
  const int phalf = wid >> 2;              // which half this wave's keys fall in

  f32x4 acc[2][4] = {};

  asm volatile("s_waitcnt vmcnt(0)" ::: "memory");
  __builtin_amdgcn_s_barrier();

  for (int c = 0; c < 32; ++c) {
    const int buf = (c & 1) * 2;
    // ---- QK^T: this wave's 16 keys x 32 queries, K=512 ----
    f32x4 s0 = {}, s1 = {};
    const half_t* kb =
        Kf + ((size_t)(bz * 256 + c * 8 + wid) * 16) * 512 + lane * 8;
#pragma unroll
    for (int ks = 0; ks < 16; ++ks) {
      half8 bk = *reinterpret_cast<const half8*>(kb + ks * 512);
      const int go = (((ks * 4 + lks) ^ qx) << 3);
      half8 a0 = *reinterpret_cast<const half8*>(&sQ[qb0 + go]);
      half8 a1 = *reinterpret_cast<const half8*>(&sQ[qb1 + go]);
      s0 = __builtin_amdgcn_mfma_f32_16x16x32_f16(a0, bk, s0, 0, 0, 0);
      s1 = __builtin_amdgcn_mfma_f32_16x16x32_f16(a1, bk, s1, 0, 0, 0);
    }
    // ---- exp -> final f32 attn + f16 sP ----
    const int key = c * 128 + wid * 16 + lrow;
#pragma unroll
    for (int m = 0; m < 2; ++m)
#pragma unroll
      for (int r = 0; r < 4; ++r) {
        const float sv = m ? s1[r] : s0[r];
        const float p = exp2f(sv * LOG2E - m2[m][r]) * il[m][r];
        const int row32 = m * 16 + lks * 4 + r;
        attnb[(size_t)(m0 + row32) * SEQ + key] = p;
        sP[buf + phalf][row32 * 64 + ((((colw >> 3) ^ (row32 & 7)) << 3) + (colw & 7))] =
            (half_t)p;
      }
    LGKM_BARRIER();
    // ---- PV: 128 keys against this wave's 64 output cols ----
#pragma unroll
    for (int kc = 0; kc < 4; ++kc) {
      const int cb = buf + (kc >> 1);
      half8 a0 = *reinterpret_cast<const half8*>(&sP[cb][aoff[0][kc & 1]]);
      half8 a1 = *reinterpret_cast<const half8*>(&sP[cb][aoff[1][kc & 1]]);
#pragma unroll
      for (int n = 0; n < 4; ++n) {
        half8 bv = *reinterpret_cast<const half8*>(
            Vfb + ((size_t)(c * 4 + kc) * 32 + n) * 512);
        acc[0][n] = __builtin_amdgcn_mfma_f32_16x16x32_f16(a0, bv, acc[0][n], 0, 0, 0);
        acc[1][n] = __builtin_amdgcn_mfma_f32_16x16x32_f16(a1, bv, acc[1][n], 0, 0, 0);
      }
    }
  }

#pragma unroll
  for (int m = 0; m < 2; ++m)
#pragma unroll
    for (int n = 0; n < 4; ++n)
#pragma unroll
      for (int r = 0; r < 4; ++r)
        Ob[(size_t)(m0 + m * 16 + lks * 4 + r) * HID + (wid * 64 + n * 16 + lrow)] =
            acc[m][n][r];
}

extern "C" void kernel_launch(void* const* d_in, const int* in_sizes, int n_in,
                              void* d_out, int out_size, void* d_ws, size_t ws_size,
                              hipStream_t stream) {
  const float* x = (const float*)d_in[0];     // [4,4096,512]
  const float* W = (const float*)d_in[1];     // [512,1536]
  const float* bias = (const float*)d_in[2];  // [1536]
  float* opt = (float*)d_out;                        // [4*4096*512]
  float* attn = opt + (size_t)NB * SEQ * HID;        // [4*4096*4096]

  half_t* xh = (half_t*)d_ws;                        // 16384*512 (dead after k_qkv)
  half_t* Wt = xh + (size_t)NB * SEQ * HID;          // 1536*512
  half_t* Qh = Wt + (size_t)N3 * HID;                // 16384*512 (scale folded)
  half_t* Kh = Qh + (size_t)NB * SEQ * HID;          // 16384*512
  half_t* Vt = Kh + (size_t)NB * SEQ * HID;          // 4*[512][4096] transposed
  half_t* Vf = Vt + (size_t)NB * HID * SEQ;          // fragment-packed V (16 MB)
  float2* part = (float2*)(Vf + (size_t)NB * HID * SEQ);  // [16384][32]
  float2* stats = part + (size_t)NB * SEQ * 32;           // [16384]
  half_t* Kf = xh;                                   // fragment-packed K (aliases xh)

  k_cvt<<<2048, 256, 0, stream>>>(x, xh, NB * SEQ * HID / 4);
  k_tw<<<dim3(N3 / 64, HID / 64), 256, 0, stream>>>(W, Wt);
  k_qkv<<<dim3(N3 / 128, NB * SEQ / 128), 256, 0, stream>>>(xh, Wt, bias, Qh, Kh, Vt);
  k_vrep<<<NB * HID * SEQ / 8 / 256, 256, 0, stream>>>(Vt, Vf);
  k_krep<<<NB * SEQ * HID / 8 / 256, 256, 0, stream>>>(Kh, Kf);
  k_stat<<<dim3(SEQ / 128, SEQ / 128, NB), 256, 0, stream>>>(Qh, Kh, part);
  k_lred<<<NB * SEQ / 256, 256, 0, stream>>>(part, stats);
  k_fa<<<512, 512, 0, stream>>>(Qh, Kf, Vf, stats, attn, opt);
}

// Round 12
// 507.333 us; speedup vs baseline: 1.0910x; 1.0910x over previous
//
#include <hip/hip_runtime.h>

#define SEQ 4096
#define HID 512
#define NB  4
#define N3  1536
#define LOG2E 1.4426950408889634f

typedef _Float16 half_t;
typedef __attribute__((ext_vector_type(8))) _Float16 half8;
typedef __attribute__((ext_vector_type(4))) float f32x4;

#define GLOAD_LDS16(gp, lp) __builtin_amdgcn_global_load_lds((gp), (lp), 16, 0, 0)

#define LGKM_BARRIER()                                                       \
  asm volatile("s_waitcnt lgkmcnt(0)" ::: "memory");                         \
  __builtin_amdgcn_sched_barrier(0);                                         \
  __builtin_amdgcn_s_barrier();

// ---------------- convert x (f32) -> f16 ----------------
__global__ void k_cvt(const float* __restrict__ x, half_t* __restrict__ xh, int n4) {
  int i = blockIdx.x * blockDim.x + threadIdx.x;
  int stride = gridDim.x * blockDim.x;
  for (; i < n4; i += stride) {
    float4 v = reinterpret_cast<const float4*>(x)[i];
    union { half_t h[4]; short4 s; } u;
    u.h[0] = (half_t)v.x; u.h[1] = (half_t)v.y;
    u.h[2] = (half_t)v.z; u.h[3] = (half_t)v.w;
    reinterpret_cast<short4*>(xh)[i] = u.s;
  }
}

// ---------------- W [512][1536] f32 -> Wt [1536][512] f16 ----------------
__global__ void k_tw(const float* __restrict__ W, half_t* __restrict__ Wt) {
  __shared__ half_t tile[64][65];
  const int n0 = blockIdx.x * 64;
  const int k0 = blockIdx.y * 64;
  const int tx = threadIdx.x & 63, ty = threadIdx.x >> 6;
#pragma unroll
  for (int i = 0; i < 64; i += 4)
    tile[ty + i][tx] = (half_t)W[(size_t)(k0 + ty + i) * N3 + n0 + tx];
  __syncthreads();
#pragma unroll
  for (int i = 0; i < 64; i += 4)
    Wt[(size_t)(n0 + ty + i) * HID + k0 + tx] = tile[tx][ty + i];
}

// ---------------- QKV projection GEMM ----------------
__launch_bounds__(256)
__global__ void k_qkv(const half_t* __restrict__ xh, const half_t* __restrict__ Wt,
                      const float* __restrict__ bias,
                      half_t* __restrict__ Qh, half_t* __restrict__ Kh,
                      half_t* __restrict__ Vt) {
  __shared__ half_t sA[128 * 32];
  __shared__ half_t sB[128 * 32];
  const int t = threadIdx.x;
  const int m0 = blockIdx.y * 128;
  const int n0 = blockIdx.x * 128;
  const int lane = t & 63, wid = t >> 6;
  const int wr = (wid >> 1) * 64, wc = (wid & 1) * 64;
  const int lrow = lane & 15, lks = lane >> 4;
  const int s1 = t, s2 = t + 256;
  const int ar1 = s1 >> 2, ac1 = (s1 & 3) * 8;
  const int ar2 = s2 >> 2, ac2 = (s2 & 3) * 8;

  f32x4 acc[4][4] = {};

  for (int k0 = 0; k0 < HID; k0 += 32) {
    __syncthreads();
    GLOAD_LDS16(xh + (size_t)(m0 + ar1) * HID + k0 + ac1, &sA[s1 * 8]);
    GLOAD_LDS16(xh + (size_t)(m0 + ar2) * HID + k0 + ac2, &sA[s2 * 8]);
    GLOAD_LDS16(Wt + (size_t)(n0 + ar1) * HID + k0 + ac1, &sB[s1 * 8]);
    GLOAD_LDS16(Wt + (size_t)(n0 + ar2) * HID + k0 + ac2, &sB[s2 * 8]);
    __syncthreads();
    half8 a[4], b[4];
#pragma unroll
    for (int m = 0; m < 4; ++m)
      a[m] = *reinterpret_cast<const half8*>(&sA[(wr + m * 16 + lrow) * 32 + lks * 8]);
#pragma unroll
    for (int n = 0; n < 4; ++n)
      b[n] = *reinterpret_cast<const half8*>(&sB[(wc + n * 16 + lrow) * 32 + lks * 8]);
#pragma unroll
    for (int m = 0; m < 4; ++m)
#pragma unroll
      for (int n = 0; n < 4; ++n)
        acc[m][n] = __builtin_amdgcn_mfma_f32_16x16x32_f16(a[m], b[n], acc[m][n], 0, 0, 0);
  }

  const float scale = 0.04419417382415922f;  // 1/sqrt(512)
  const int region = n0 >> 9;  // 0=Q, 1=K, 2=V (uniform per block)
#pragma unroll
  for (int m = 0; m < 4; ++m) {
#pragma unroll
    for (int n = 0; n < 4; ++n) {
      const int col = n0 + wc + n * 16 + lrow;
#pragma unroll
      for (int r = 0; r < 4; ++r) {
        const int row = m0 + wr + m * 16 + lks * 4 + r;
        float v = acc[m][n][r] + bias[col];
        if (region == 0) {
          Qh[(size_t)row * HID + col] = (half_t)(v * scale);
        } else if (region == 1) {
          Kh[(size_t)row * HID + (col - 512)] = (half_t)v;
        } else {
          const int bb = row >> 12, ml = row & (SEQ - 1);
          Vt[((size_t)bb * HID + (col - 1024)) * SEQ + ml] = (half_t)v;
        }
      }
    }
  }
}

// ---------------- repack Vt [b][h][s] -> Vf MFMA-fragment tiles ----------------
__global__ void k_vrep(const half_t* __restrict__ Vt, half_t* __restrict__ Vf) {
  const int g = blockIdx.x * 256 + threadIdx.x;   // one half8 per thread
  const int tile = g >> 6, l = g & 63;
  const int bb = tile >> 12;
  const int kc = (tile >> 5) & 127;
  const int hg = tile & 31;
  const int h = hg * 16 + (l & 15);
  const int s = kc * 32 + (l >> 4) * 8;
  half8 v = *reinterpret_cast<const half8*>(&Vt[((size_t)bb * HID + h) * SEQ + s]);
  *reinterpret_cast<half8*>(&Vf[(size_t)tile * 512 + l * 8]) = v;
}

// ---------------- scores = Q @ K^T -> f16 Sh (packed in attn region) + partials --
__launch_bounds__(256)
__global__ void k_qk(const half_t* __restrict__ Qh, const half_t* __restrict__ Kh,
                     float* __restrict__ S, float2* __restrict__ part) {
  __shared__ half_t sA[128 * 32];
  __shared__ half_t sB[128 * 32];
  __shared__ float lm[2][128], ls[2][128];
  const int t = threadIdx.x;
  const int bz = blockIdx.z;
  const half_t* A = Qh + (size_t)bz * SEQ * HID;
  const half_t* B = Kh + (size_t)bz * SEQ * HID;
  half_t* Ch = (half_t*)(S + (size_t)bz * SEQ * SEQ);
  const int m0 = blockIdx.y * 128;
  const int n0 = blockIdx.x * 128;
  const int lane = t & 63, wid = t >> 6;
  const int wr = (wid >> 1) * 64, wc = (wid & 1) * 64;
  const int lrow = lane & 15, lks = lane >> 4;
  const int s1 = t, s2 = t + 256;
  const int ar1 = s1 >> 2, ac1 = (s1 & 3) * 8;
  const int ar2 = s2 >> 2, ac2 = (s2 & 3) * 8;

  f32x4 acc[4][4] = {};

  for (int k0 = 0; k0 < HID; k0 += 32) {
    __syncthreads();
    GLOAD_LDS16(A + (size_t)(m0 + ar1) * HID + k0 + ac1, &sA[s1 * 8]);
    GLOAD_LDS16(A + (size_t)(m0 + ar2) * HID + k0 + ac2, &sA[s2 * 8]);
    GLOAD_LDS16(B + (size_t)(n0 + ar1) * HID + k0 + ac1, &sB[s1 * 8]);
    GLOAD_LDS16(B + (size_t)(n0 + ar2) * HID + k0 + ac2, &sB[s2 * 8]);
    __syncthreads();
    half8 a[4], b[4];
#pragma unroll
    for (int m = 0; m < 4; ++m)
      a[m] = *reinterpret_cast<const half8*>(&sA[(wr + m * 16 + lrow) * 32 + lks * 8]);
#pragma unroll
    for (int n = 0; n < 4; ++n)
      b[n] = *reinterpret_cast<const half8*>(&sB[(wc + n * 16 + lrow) * 32 + lks * 8]);
#pragma unroll
    for (int m = 0; m < 4; ++m)
#pragma unroll
      for (int n = 0; n < 4; ++n)
        acc[m][n] = __builtin_amdgcn_mfma_f32_16x16x32_f16(a[m], b[n], acc[m][n], 0, 0, 0);
  }

  // f16 raw-score write into the packed Sh slots
#pragma unroll
  for (int m = 0; m < 4; ++m)
#pragma unroll
    for (int n = 0; n < 4; ++n)
#pragma unroll
      for (int r = 0; r < 4; ++r)
        Ch[(size_t)(m0 + wr + m * 16 + lks * 4 + r) * (2 * SEQ) + SEQ +
           (n0 + wc + n * 16 + lrow)] = (half_t)acc[m][n][r];

  // per-tile softmax partials
#pragma unroll
  for (int m = 0; m < 4; ++m) {
#pragma unroll
    for (int r = 0; r < 4; ++r) {
      float mx = fmaxf(fmaxf(acc[m][0][r], acc[m][1][r]),
                       fmaxf(acc[m][2][r], acc[m][3][r]));
      mx = fmaxf(mx, __shfl_xor(mx, 1));
      mx = fmaxf(mx, __shfl_xor(mx, 2));
      mx = fmaxf(mx, __shfl_xor(mx, 4));
      mx = fmaxf(mx, __shfl_xor(mx, 8));
      float s = expf(acc[m][0][r] - mx) + expf(acc[m][1][r] - mx) +
                expf(acc[m][2][r] - mx) + expf(acc[m][3][r] - mx);
      s += __shfl_xor(s, 1);
      s += __shfl_xor(s, 2);
      s += __shfl_xor(s, 4);
      s += __shfl_xor(s, 8);
      if (lrow == 0) {
        const int rr = wr + m * 16 + lks * 4 + r;
        lm[wid & 1][rr] = mx;
        ls[wid & 1][rr] = s;
      }
    }
  }
  __syncthreads();
  if (t < 128) {
    const float m0v = lm[0][t], m1v = lm[1][t];
    const float M = fmaxf(m0v, m1v);
    const float L = ls[0][t] * expf(m0v - M) + ls[1][t] * expf(m1v - M);
    part[(size_t)(bz * SEQ + m0 + t) * 32 + blockIdx.x] = make_float2(M, L);
  }
}

// ---------------- merge 32 per-tile partials per row -> (rowmax, 1/rowsum) --------
__global__ void k_lred(const float2* __restrict__ part, float2* __restrict__ stats) {
  const int row = blockIdx.x * 256 + threadIdx.x;  // [0, NB*SEQ)
  const float2* p = part + (size_t)row * 32;
  float M = -3.4028235e38f;
#pragma unroll
  for (int i = 0; i < 32; ++i) M = fmaxf(M, p[i].x);
  float L = 0.f;
#pragma unroll
  for (int i = 0; i < 32; ++i) L += p[i].y * expf(p[i].x - M);
  stats[row] = make_float2(M, 1.0f / L);
}

// ---------------- fused: read f16 Sh -> write f32 attn + opt = attn @ V ----------
// BM=64, BN=512, chunk=64 keys (64 iters). 8 waves, each owns 64 rows x 64 cols
// (wave grid 1x8 -> ZERO V duplication: each wave loads 8 distinct 1KB frags/chunk;
// block V traffic 64KB/chunk distinct = 1.05 GB total, half of R9).
// Register Sh prefetch (1-chunk lead), 128B-row XOR-swizzled sA (R9's measured
// 0-conflict pattern), lgkm-only barriers, plain f32 attn stores.
// In-place: write end 256c+256 <= read front 8192+128c+256 for all c.
__launch_bounds__(512, 2)
__global__ void k_pvn(float* __restrict__ P, const half_t* __restrict__ Vf,
                      const float2* __restrict__ stats, float* __restrict__ O) {
  __shared__ half_t sA[2][64 * 64];   // 2 x 8 KB, XOR-swizzled
  const int t = threadIdx.x;

  // bijective XCD swizzle: 256 blocks, 32 per XCD
  const int bid = blockIdx.x;
  const int sw = (bid & 7) * 32 + (bid >> 3);
  const int bz = sw >> 6;
  const int m0 = (sw & 63) * 64;

  float* Pb = P + (size_t)bz * SEQ * SEQ;
  const half_t* Vfb = Vf + (size_t)bz * 128 * 32 * 512;
  float* Ob = O + (size_t)bz * SEQ * HID;

  const int lane = t & 63, wid = t >> 6;
  const int lrow = lane & 15, lks = lane >> 4;

  // Sh / attn per-thread map: thread owns 8 keys (granule tk8) of row trow
  const int trow = t >> 3;   // 0..63
  const int tk8 = t & 7;     // key granule within 64-key chunk
  const float2 st = stats[(size_t)bz * SEQ + m0 + trow];
  const float mrow2 = st.x * LOG2E, invl = st.y;
  float* const PArow = Pb + (size_t)(m0 + trow) * SEQ + tk8 * 8;
  const half_t* const Shrow =
      (const half_t*)(Pb + (size_t)(m0 + trow) * SEQ) + SEQ + tk8 * 8;
  const int aswz = trow * 64 + ((tk8 ^ (trow & 7)) << 3);

  // a-frag swizzled read offsets: wave reads ALL 64 rows (m=0..3)
  int aoff[4][2];
#pragma unroll
  for (int m = 0; m < 4; ++m)
#pragma unroll
    for (int kk = 0; kk < 2; ++kk) {
      const int row = m * 16 + lrow;
      aoff[m][kk] = row * 64 + (((kk * 4 + lks) ^ (row & 7)) << 3);
    }

  // V frag base: frag (kc=c*2+kk, hg=wid*4+n) at vb + (kc*32 + n)*512
  const half_t* const vb = Vfb + (size_t)(wid * 4) * 512 + lane * 8;

  f32x4 acc[4][4] = {};
  half8 pr;

#define PV_EXPSTAGE(BUF, PR8, CW)                                            \
  {                                                                          \
    f32x4 ev0, ev1;                                                          \
    _Pragma("unroll")                                                        \
    for (int j = 0; j < 4; ++j) {                                            \
      ev0[j] = exp2f((float)(PR8)[j] * LOG2E - mrow2) * invl;                \
      ev1[j] = exp2f((float)(PR8)[j + 4] * LOG2E - mrow2) * invl;            \
    }                                                                        \
    half8 hv;                                                                \
    _Pragma("unroll")                                                        \
    for (int j = 0; j < 4; ++j) {                                            \
      hv[j] = (half_t)ev0[j];                                                \
      hv[j + 4] = (half_t)ev1[j];                                            \
    }                                                                        \
    *reinterpret_cast<half8*>(&sA[BUF][aswz]) = hv;                          \
    *reinterpret_cast<f32x4*>(PArow + (CW) * 64) = ev0;                      \
    *reinterpret_cast<f32x4*>(PArow + (CW) * 64 + 4) = ev1;                  \
  }

  // ---- prologue: consume Sh(0); load pr <- Sh(1) ----
  {
    half8 p0 = *reinterpret_cast<const half8*>(Shrow);
    PV_EXPSTAGE(0, p0, 0);
    pr = *reinterpret_cast<const half8*>(Shrow + 64);
    LGKM_BARRIER();
  }

  for (int c = 0; c < 64; ++c) {
    const int cur = c & 1;
    // ---- MFMA: 64 keys x (this wave's 64 cols) x 64 rows ----
#pragma unroll
    for (int kk = 0; kk < 2; ++kk) {
      half8 a[4];
#pragma unroll
      for (int m = 0; m < 4; ++m)
        a[m] = *reinterpret_cast<const half8*>(&sA[cur][aoff[m][kk]]);
#pragma unroll
      for (int n = 0; n < 4; ++n) {
        half8 bv = *reinterpret_cast<const half8*>(
            vb + ((size_t)((c * 2 + kk) * 32 + n)) * 512);
#pragma unroll
        for (int m = 0; m < 4; ++m)
          acc[m][n] = __builtin_amdgcn_mfma_f32_16x16x32_f16(a[m], bv,
                                                             acc[m][n], 0, 0, 0);
      }
    }
    // ---- consume Sh(c+1) (prefetched last iter): exp -> sA[nxt] + attn store ----
    if (c + 1 < 64) {
      PV_EXPSTAGE(cur ^ 1, pr, c + 1);
      if (c + 2 < 64)
        pr = *reinterpret_cast<const half8*>(Shrow + (c + 2) * 64);
    }
    LGKM_BARRIER();
  }

#pragma unroll
  for (int m = 0; m < 4; ++m)
#pragma unroll
    for (int n = 0; n < 4; ++n)
#pragma unroll
      for (int r = 0; r < 4; ++r)
        Ob[(size_t)(m0 + m * 16 + lks * 4 + r) * HID + (wid * 64 + n * 16 + lrow)] =
            acc[m][n][r];
}

extern "C" void kernel_launch(void* const* d_in, const int* in_sizes, int n_in,
                              void* d_out, int out_size, void* d_ws, size_t ws_size,
                              hipStream_t stream) {
  const float* x = (const float*)d_in[0];     // [4,4096,512]
  const float* W = (const float*)d_in[1];     // [512,1536]
  const float* bias = (const float*)d_in[2];  // [1536]
  float* opt = (float*)d_out;                        // [4*4096*512]
  float* attn = opt + (size_t)NB * SEQ * HID;        // [4*4096*4096]

  half_t* xh = (half_t*)d_ws;                        // 16384*512
  half_t* Wt = xh + (size_t)NB * SEQ * HID;          // 1536*512
  half_t* Qh = Wt + (size_t)N3 * HID;                // 16384*512 (scale folded)
  half_t* Kh = Qh + (size_t)NB * SEQ * HID;          // 16384*512
  half_t* Vt = Kh + (size_t)NB * SEQ * HID;          // 4*[512][4096] transposed
  half_t* Vf = Vt + (size_t)NB * HID * SEQ;          // fragment-packed V (16 MB)
  float2* part = (float2*)(Vf + (size_t)NB * HID * SEQ);  // [16384][32]
  float2* stats = part + (size_t)NB * SEQ * 32;           // [16384]

  k_cvt<<<2048, 256, 0, stream>>>(x, xh, NB * SEQ * HID / 4);
  k_tw<<<dim3(N3 / 64, HID / 64), 256, 0, stream>>>(W, Wt);
  k_qkv<<<dim3(N3 / 128, NB * SEQ / 128), 256, 0, stream>>>(xh, Wt, bias, Qh, Kh, Vt);
  k_vrep<<<NB * HID * SEQ / 8 / 256, 256, 0, stream>>>(Vt, Vf);
  k_qk<<<dim3(SEQ / 128, SEQ / 128, NB), 256, 0, stream>>>(Qh, Kh, attn, part);
  k_lred<<<NB * SEQ / 256, 256, 0, stream>>>(part, stats);
  k_pvn<<<256, 512, 0, stream>>>(attn, Vf, stats, opt);
}

// Round 13
// 425.009 us; speedup vs baseline: 1.3023x; 1.1937x over previous
//
#include <hip/hip_runtime.h>

#define SEQ 4096
#define HID 512
#define NB  4
#define N3  1536
#define LOG2E 1.4426950408889634f

typedef _Float16 half_t;
typedef __attribute__((ext_vector_type(8))) _Float16 half8;
typedef __attribute__((ext_vector_type(4))) float f32x4;

#define GLOAD_LDS16(gp, lp) __builtin_amdgcn_global_load_lds((gp), (lp), 16, 0, 0)

#define LGKM_BARRIER()                                                       \
  asm volatile("s_waitcnt lgkmcnt(0)" ::: "memory");                         \
  __builtin_amdgcn_sched_barrier(0);                                         \
  __builtin_amdgcn_s_barrier();

// ---------------- convert x (f32) -> f16 ----------------
__global__ void k_cvt(const float* __restrict__ x, half_t* __restrict__ xh, int n4) {
  int i = blockIdx.x * blockDim.x + threadIdx.x;
  int stride = gridDim.x * blockDim.x;
  for (; i < n4; i += stride) {
    float4 v = reinterpret_cast<const float4*>(x)[i];
    union { half_t h[4]; short4 s; } u;
    u.h[0] = (half_t)v.x; u.h[1] = (half_t)v.y;
    u.h[2] = (half_t)v.z; u.h[3] = (half_t)v.w;
    reinterpret_cast<short4*>(xh)[i] = u.s;
  }
}

// ---------------- W [512][1536] f32 -> Wt [1536][512] f16 ----------------
__global__ void k_tw(const float* __restrict__ W, half_t* __restrict__ Wt) {
  __shared__ half_t tile[64][65];
  const int n0 = blockIdx.x * 64;
  const int k0 = blockIdx.y * 64;
  const int tx = threadIdx.x & 63, ty = threadIdx.x >> 6;
#pragma unroll
  for (int i = 0; i < 64; i += 4)
    tile[ty + i][tx] = (half_t)W[(size_t)(k0 + ty + i) * N3 + n0 + tx];
  __syncthreads();
#pragma unroll
  for (int i = 0; i < 64; i += 4)
    Wt[(size_t)(n0 + ty + i) * HID + k0 + tx] = tile[tx][ty + i];
}

// ---------------- QKV projection GEMM (V written fragment-packed) ----------------
__launch_bounds__(256)
__global__ void k_qkv(const half_t* __restrict__ xh, const half_t* __restrict__ Wt,
                      const float* __restrict__ bias,
                      half_t* __restrict__ Qh, half_t* __restrict__ Kh,
                      half_t* __restrict__ Vf) {
  __shared__ half_t sA[128 * 32];
  __shared__ half_t sB[128 * 32];
  const int t = threadIdx.x;
  const int m0 = blockIdx.y * 128;
  const int n0 = blockIdx.x * 128;
  const int lane = t & 63, wid = t >> 6;
  const int wr = (wid >> 1) * 64, wc = (wid & 1) * 64;
  const int lrow = lane & 15, lks = lane >> 4;
  const int s1 = t, s2 = t + 256;
  const int ar1 = s1 >> 2, ac1 = (s1 & 3) * 8;
  const int ar2 = s2 >> 2, ac2 = (s2 & 3) * 8;

  f32x4 acc[4][4] = {};

  for (int k0 = 0; k0 < HID; k0 += 32) {
    __syncthreads();
    GLOAD_LDS16(xh + (size_t)(m0 + ar1) * HID + k0 + ac1, &sA[s1 * 8]);
    GLOAD_LDS16(xh + (size_t)(m0 + ar2) * HID + k0 + ac2, &sA[s2 * 8]);
    GLOAD_LDS16(Wt + (size_t)(n0 + ar1) * HID + k0 + ac1, &sB[s1 * 8]);
    GLOAD_LDS16(Wt + (size_t)(n0 + ar2) * HID + k0 + ac2, &sB[s2 * 8]);
    __syncthreads();
    half8 a[4], b[4];
#pragma unroll
    for (int m = 0; m < 4; ++m)
      a[m] = *reinterpret_cast<const half8*>(&sA[(wr + m * 16 + lrow) * 32 + lks * 8]);
#pragma unroll
    for (int n = 0; n < 4; ++n)
      b[n] = *reinterpret_cast<const half8*>(&sB[(wc + n * 16 + lrow) * 32 + lks * 8]);
#pragma unroll
    for (int m = 0; m < 4; ++m)
#pragma unroll
      for (int n = 0; n < 4; ++n)
        acc[m][n] = __builtin_amdgcn_mfma_f32_16x16x32_f16(a[m], b[n], acc[m][n], 0, 0, 0);
  }

  const float scale = 0.04419417382415922f;  // 1/sqrt(512)
  const int region = n0 >> 9;  // 0=Q, 1=K, 2=V (uniform per block)
#pragma unroll
  for (int m = 0; m < 4; ++m) {
#pragma unroll
    for (int n = 0; n < 4; ++n) {
      const int col = n0 + wc + n * 16 + lrow;
#pragma unroll
      for (int r = 0; r < 4; ++r) {
        const int row = m0 + wr + m * 16 + lks * 4 + r;
        float v = acc[m][n][r] + bias[col];
        if (region == 0) {
          Qh[(size_t)row * HID + col] = (half_t)(v * scale);
        } else if (region == 1) {
          Kh[(size_t)row * HID + (col - 512)] = (half_t)v;
        } else {
          const int bb = row >> 12, s = row & (SEQ - 1), h = col - 1024;
          const int tl = bb * 4096 + (s >> 5) * 32 + (h >> 4);
          Vf[(size_t)tl * 512 + (((h & 15) | (((s >> 3) & 3) << 4)) * 8) + (s & 7)] =
              (half_t)v;
        }
      }
    }
  }
}

// ---------------- scores = Q @ K^T -> f16 raw scores + softmax partials ----------
// FRAG=1: fragment-packed Shf tiles (16 rows x 32 keys, MFMA-A lane order).
// FRAG=0: row-packed into attn rows' upper halves (fallback).
template <int FRAG>
__launch_bounds__(256)
__global__ void k_qk(const half_t* __restrict__ Qh, const half_t* __restrict__ Kh,
                     half_t* __restrict__ Sh, float2* __restrict__ part) {
  __shared__ half_t sA[128 * 32];
  __shared__ half_t sB[128 * 32];
  __shared__ float lm[2][128], ls[2][128];
  const int t = threadIdx.x;
  const int bz = blockIdx.z;
  const half_t* A = Qh + (size_t)bz * SEQ * HID;
  const half_t* B = Kh + (size_t)bz * SEQ * HID;
  const int m0 = blockIdx.y * 128;
  const int n0 = blockIdx.x * 128;
  const int lane = t & 63, wid = t >> 6;
  const int wr = (wid >> 1) * 64, wc = (wid & 1) * 64;
  const int lrow = lane & 15, lks = lane >> 4;
  const int s1 = t, s2 = t + 256;
  const int ar1 = s1 >> 2, ac1 = (s1 & 3) * 8;
  const int ar2 = s2 >> 2, ac2 = (s2 & 3) * 8;

  f32x4 acc[4][4] = {};

  for (int k0 = 0; k0 < HID; k0 += 32) {
    __syncthreads();
    GLOAD_LDS16(A + (size_t)(m0 + ar1) * HID + k0 + ac1, &sA[s1 * 8]);
    GLOAD_LDS16(A + (size_t)(m0 + ar2) * HID + k0 + ac2, &sA[s2 * 8]);
    GLOAD_LDS16(B + (size_t)(n0 + ar1) * HID + k0 + ac1, &sB[s1 * 8]);
    GLOAD_LDS16(B + (size_t)(n0 + ar2) * HID + k0 + ac2, &sB[s2 * 8]);
    __syncthreads();
    half8 a[4], b[4];
#pragma unroll
    for (int m = 0; m < 4; ++m)
      a[m] = *reinterpret_cast<const half8*>(&sA[(wr + m * 16 + lrow) * 32 + lks * 8]);
#pragma unroll
    for (int n = 0; n < 4; ++n)
      b[n] = *reinterpret_cast<const half8*>(&sB[(wc + n * 16 + lrow) * 32 + lks * 8]);
#pragma unroll
    for (int m = 0; m < 4; ++m)
#pragma unroll
      for (int n = 0; n < 4; ++n)
        acc[m][n] = __builtin_amdgcn_mfma_f32_16x16x32_f16(a[m], b[n], acc[m][n], 0, 0, 0);
  }

  // f16 raw-score write
#pragma unroll
  for (int m = 0; m < 4; ++m)
#pragma unroll
    for (int n = 0; n < 4; ++n)
#pragma unroll
      for (int r = 0; r < 4; ++r) {
        const int row = m0 + wr + m * 16 + lks * 4 + r;
        const int key = n0 + wc + n * 16 + lrow;
        if (FRAG) {
          Sh[((size_t)(bz * 128 + (key >> 5)) * 256 + (row >> 4)) * 512 +
             (((row & 15) | (((key >> 3) & 3) << 4)) * 8) + (key & 7)] =
              (half_t)acc[m][n][r];
        } else {
          Sh[((size_t)bz * SEQ + row) * (2 * SEQ) + SEQ + key] = (half_t)acc[m][n][r];
        }
      }

  // per-tile softmax partials
#pragma unroll
  for (int m = 0; m < 4; ++m) {
#pragma unroll
    for (int r = 0; r < 4; ++r) {
      float mx = fmaxf(fmaxf(acc[m][0][r], acc[m][1][r]),
                       fmaxf(acc[m][2][r], acc[m][3][r]));
      mx = fmaxf(mx, __shfl_xor(mx, 1));
      mx = fmaxf(mx, __shfl_xor(mx, 2));
      mx = fmaxf(mx, __shfl_xor(mx, 4));
      mx = fmaxf(mx, __shfl_xor(mx, 8));
      float s = expf(acc[m][0][r] - mx) + expf(acc[m][1][r] - mx) +
                expf(acc[m][2][r] - mx) + expf(acc[m][3][r] - mx);
      s += __shfl_xor(s, 1);
      s += __shfl_xor(s, 2);
      s += __shfl_xor(s, 4);
      s += __shfl_xor(s, 8);
      if (lrow == 0) {
        const int rr = wr + m * 16 + lks * 4 + r;
        lm[wid & 1][rr] = mx;
        ls[wid & 1][rr] = s;
      }
    }
  }
  __syncthreads();
  if (t < 128) {
    const float m0v = lm[0][t], m1v = lm[1][t];
    const float M = fmaxf(m0v, m1v);
    const float L = ls[0][t] * expf(m0v - M) + ls[1][t] * expf(m1v - M);
    part[(size_t)(bz * SEQ + m0 + t) * 32 + blockIdx.x] = make_float2(M, L);
  }
}

// ---------------- merge 32 per-tile partials per row -> (rowmax, 1/rowsum) --------
__global__ void k_lred(const float2* __restrict__ part, float2* __restrict__ stats) {
  const int row = blockIdx.x * 256 + threadIdx.x;  // [0, NB*SEQ)
  const float2* p = part + (size_t)row * 32;
  float M = -3.4028235e38f;
#pragma unroll
  for (int i = 0; i < 32; ++i) M = fmaxf(M, p[i].x);
  float L = 0.f;
#pragma unroll
  for (int i = 0; i < 32; ++i) L += p[i].y * expf(p[i].x - M);
  stats[row] = make_float2(M, 1.0f / L);
}

// ---------------- BARRIER-FREE fused PV (primary path) ----------------
// Block = 64 rows x 512 cols, 8 waves each 64x64, NO LDS, NO __syncthreads.
// A-frags load contiguous from fragment-packed Shf; exp in-register (lane only
// needs stats of its 4 rows); designated wave (kc&7) writes the f32 attn chunk;
// MFMA feeds directly from registers. 16 waves/CU drift freely -> TLP hides
// all memory latency. chunk = 32 keys, 128 chunks.
__launch_bounds__(512, 2)
__global__ void k_pvf(const half_t* __restrict__ Shf, const half_t* __restrict__ Vf,
                      const float2* __restrict__ stats,
                      float* __restrict__ attn, float* __restrict__ O) {
  const int t = threadIdx.x;
  const int bid = blockIdx.x;
  const int sw = (bid & 7) * 32 + (bid >> 3);  // 256 blocks, 32/XCD
  const int bz = sw >> 6;
  const int s64 = sw & 63;
  const int m0 = s64 * 64;
  const int lane = t & 63, wid = t >> 6;
  const int lrow = lane & 15, lks = lane >> 4;

  float* attnb = attn + (size_t)bz * SEQ * SEQ;
  float* Ob = O + (size_t)bz * SEQ * HID;

  float m2[4], il[4];
#pragma unroll
  for (int m = 0; m < 4; ++m) {
    float2 st = stats[(size_t)bz * SEQ + m0 + m * 16 + lrow];
    m2[m] = st.x * LOG2E;
    il[m] = st.y;
  }

  const half_t* const abase =
      Shf + ((size_t)(bz * 128) * 256 + s64 * 4) * 512 + lane * 8;
  const half_t* const vbase =
      Vf + ((size_t)bz * 4096 + wid * 4) * 512 + lane * 8;

  f32x4 acc[4][4] = {};

  for (int kc = 0; kc < 128; ++kc) {
    half8 ar[4], bv[4], ah[4];
#pragma unroll
    for (int m = 0; m < 4; ++m)
      ar[m] = *reinterpret_cast<const half8*>(abase + ((size_t)kc * 256 + m) * 512);
#pragma unroll
    for (int n = 0; n < 4; ++n)
      bv[n] = *reinterpret_cast<const half8*>(vbase + ((size_t)kc * 32 + n) * 512);

    const bool wstore = (wid == (kc & 7));
#pragma unroll
    for (int m = 0; m < 4; ++m) {
      f32x4 e0, e1;
#pragma unroll
      for (int j = 0; j < 4; ++j) {
        e0[j] = exp2f((float)ar[m][j] * LOG2E - m2[m]) * il[m];
        e1[j] = exp2f((float)ar[m][j + 4] * LOG2E - m2[m]) * il[m];
      }
#pragma unroll
      for (int j = 0; j < 4; ++j) {
        ah[m][j] = (half_t)e0[j];
        ah[m][j + 4] = (half_t)e1[j];
      }
      if (wstore) {
        float* p = attnb + (size_t)(m0 + m * 16 + lrow) * SEQ + kc * 32 + lks * 8;
        *reinterpret_cast<f32x4*>(p) = e0;
        *reinterpret_cast<f32x4*>(p + 4) = e1;
      }
    }
#pragma unroll
    for (int m = 0; m < 4; ++m)
#pragma unroll
      for (int n = 0; n < 4; ++n)
        acc[m][n] = __builtin_amdgcn_mfma_f32_16x16x32_f16(ah[m], bv[n], acc[m][n], 0, 0, 0);
  }

#pragma unroll
  for (int m = 0; m < 4; ++m)
#pragma unroll
    for (int n = 0; n < 4; ++n)
#pragma unroll
      for (int r = 0; r < 4; ++r)
        Ob[(size_t)(m0 + m * 16 + lks * 4 + r) * HID + (wid * 64 + n * 16 + lrow)] =
            acc[m][n][r];
}

// ---------------- fallback PV (R9 known-good: 203us) ----------------
__launch_bounds__(512, 4)
__global__ void k_pvn(float* __restrict__ P, const half_t* __restrict__ Vf,
                      const float2* __restrict__ stats, float* __restrict__ O) {
  __shared__ half_t sA[4][32 * 64];
  const int t = threadIdx.x;
  const int bid = blockIdx.x;
  const int sw = (bid & 7) * 64 + (bid >> 3);
  const int bz = sw >> 7;
  const int m0 = (sw & 127) * 32;

  float* Pb = P + (size_t)bz * SEQ * SEQ;
  float* Ob = O + (size_t)bz * SEQ * HID;

  const int lane = t & 63, wid = t >> 6;
  const int lrow = lane & 15, lks = lane >> 4;

  const int prow = t >> 4;
  const int pc = t & 15;
  const float2 st = stats[(size_t)bz * SEQ + m0 + prow];
  const float mrow2 = st.x * LOG2E, invl = st.y;

  float* const PArow = Pb + (size_t)(m0 + prow) * SEQ + pc * 8;
  const half_t* const Shrow =
      (const half_t*)(Pb + (size_t)(m0 + prow) * SEQ) + SEQ + pc * 8;

  const int schunk = pc >> 3;
  const int sidx = prow * 64 + (((pc & 7) ^ (prow & 7)) << 3);

  int aoff[2][2];
#pragma unroll
  for (int m = 0; m < 2; ++m)
#pragma unroll
    for (int kk = 0; kk < 2; ++kk) {
      const int row = m * 16 + lrow;
      aoff[m][kk] = row * 64 + (((kk * 4 + lks) ^ (row & 7)) << 3);
    }

  const half_t* const vb =
      Vf + (size_t)bz * 4096 * 512 + (size_t)(wid * 4) * 512 + lane * 8;

  f32x4 acc[2][4] = {};
  f32x4 e0, e1;
  half8 prA, prB;

#define PV_EXPSTAGE(SB, PR)                                                  \
  {                                                                          \
    _Pragma("unroll")                                                        \
    for (int j = 0; j < 4; ++j) {                                            \
      e0[j] = exp2f((float)(PR)[j] * LOG2E - mrow2) * invl;                  \
      e1[j] = exp2f((float)(PR)[j + 4] * LOG2E - mrow2) * invl;              \
    }                                                                        \
    half8 hv;                                                                \
    _Pragma("unroll")                                                        \
    for (int j = 0; j < 4; ++j) {                                            \
      hv[j] = (half_t)e0[j];                                                 \
      hv[j + 4] = (half_t)e1[j];                                             \
    }                                                                        \
    *reinterpret_cast<half8*>(&sA[(SB) * 2 + schunk][sidx]) = hv;            \
  }

#define PV_ITER(PRL, PRC, SC)                                                \
  {                                                                          \
    half8 b[16];                                                             \
    _Pragma("unroll")                                                        \
    for (int kc = 0; kc < 4; ++kc)                                           \
      _Pragma("unroll")                                                      \
      for (int n = 0; n < 4; ++n)                                            \
        b[kc * 4 + n] = *reinterpret_cast<const half8*>(                     \
            vb + ((size_t)((SC) * 4 + kc) * 32 + n) * 512);                  \
    if ((SC) + 2 < 32)                                                       \
      PRL = *reinterpret_cast<const half8*>(Shrow + ((SC) + 2) * 128);       \
    *reinterpret_cast<f32x4*>(PArow + (SC) * 128) = e0;                      \
    *reinterpret_cast<f32x4*>(PArow + (SC) * 128 + 4) = e1;                  \
    __builtin_amdgcn_sched_barrier(0);                                       \
    _Pragma("unroll")                                                        \
    for (int kc = 0; kc < 4; ++kc) {                                         \
      const int cb = ((SC) & 1) * 2 + (kc >> 1);                             \
      half8 a[2];                                                            \
      _Pragma("unroll")                                                      \
      for (int m = 0; m < 2; ++m)                                            \
        a[m] = *reinterpret_cast<const half8*>(&sA[cb][aoff[m][kc & 1]]);    \
      _Pragma("unroll")                                                      \
      for (int m = 0; m < 2; ++m)                                            \
        _Pragma("unroll")                                                    \
        for (int n = 0; n < 4; ++n)                                          \
          acc[m][n] = __builtin_amdgcn_mfma_f32_16x16x32_f16(                \
              a[m], b[kc * 4 + n], acc[m][n], 0, 0, 0);                      \
    }                                                                        \
    if ((SC) + 1 < 32) {                                                     \
      PV_EXPSTAGE(((SC) + 1) & 1, PRC);                                      \
    }                                                                        \
    LGKM_BARRIER();                                                          \
  }

  {
    half8 pr0 = *reinterpret_cast<const half8*>(Shrow);
    PV_EXPSTAGE(0, pr0);
    prB = *reinterpret_cast<const half8*>(Shrow + 128);
    LGKM_BARRIER();
  }

  for (int sc = 0; sc < 32; sc += 2) {
    PV_ITER(prA, prB, sc);
    PV_ITER(prB, prA, sc + 1);
  }

#pragma unroll
  for (int m = 0; m < 2; ++m)
#pragma unroll
    for (int n = 0; n < 4; ++n)
#pragma unroll
      for (int r = 0; r < 4; ++r)
        Ob[(size_t)(m0 + m * 16 + lks * 4 + r) * HID + (wid * 64 + n * 16 + lrow)] =
            acc[m][n][r];
}

extern "C" void kernel_launch(void* const* d_in, const int* in_sizes, int n_in,
                              void* d_out, int out_size, void* d_ws, size_t ws_size,
                              hipStream_t stream) {
  const float* x = (const float*)d_in[0];     // [4,4096,512]
  const float* W = (const float*)d_in[1];     // [512,1536]
  const float* bias = (const float*)d_in[2];  // [1536]
  float* opt = (float*)d_out;                        // [4*4096*512]
  float* attn = opt + (size_t)NB * SEQ * HID;        // [4*4096*4096]

  half_t* xh = (half_t*)d_ws;                        // 16.78 MB
  half_t* Wt = xh + (size_t)NB * SEQ * HID;          // 1.57 MB
  half_t* Qh = Wt + (size_t)N3 * HID;                // 16.78 MB
  half_t* Kh = Qh + (size_t)NB * SEQ * HID;          // 16.78 MB
  half_t* Vf = Kh + (size_t)NB * SEQ * HID;          // 16.78 MB (fragment-packed)
  float2* part = (float2*)(Vf + (size_t)NB * HID * SEQ);  // 4.19 MB
  float2* stats = part + (size_t)NB * SEQ * 32;           // 131 KB
  half_t* Shf = (half_t*)(stats + NB * SEQ);              // 134.2 MB (frag scores)
  const size_t need = (size_t)((char*)(Shf + (size_t)NB * SEQ * SEQ) - (char*)d_ws);
  const bool frag = ws_size >= need;

  k_cvt<<<2048, 256, 0, stream>>>(x, xh, NB * SEQ * HID / 4);
  k_tw<<<dim3(N3 / 64, HID / 64), 256, 0, stream>>>(W, Wt);
  k_qkv<<<dim3(N3 / 128, NB * SEQ / 128), 256, 0, stream>>>(xh, Wt, bias, Qh, Kh, Vf);
  if (frag) {
    k_qk<1><<<dim3(SEQ / 128, SEQ / 128, NB), 256, 0, stream>>>(Qh, Kh, Shf, part);
    k_lred<<<NB * SEQ / 256, 256, 0, stream>>>(part, stats);
    k_pvf<<<256, 512, 0, stream>>>(Shf, Vf, stats, attn, opt);
  } else {
    k_qk<0><<<dim3(SEQ / 128, SEQ / 128, NB), 256, 0, stream>>>(Qh, Kh, (half_t*)attn,
                                                                part);
    k_lred<<<NB * SEQ / 256, 256, 0, stream>>>(part, stats);
    k_pvn<<<512, 512, 0, stream>>>(attn, Vf, stats, opt);
  }
}